// Round 7
// baseline (257.473 us; speedup 1.0000x reference)
//
#include <hip/hip_runtime.h>
#include <hip/hip_bf16.h>

#define DIM   1024
#define BATCH 8192
#define KV    16

typedef __attribute__((ext_vector_type(4))) float f32x4;
typedef __attribute__((ext_vector_type(8))) short short8;

static __device__ __forceinline__ unsigned short f2bf(float x) {
  return __builtin_bit_cast(unsigned short, __float2bfloat16(x));
}
static __device__ __forceinline__ float bf2f(unsigned short x) {
  return __bfloat162float(__builtin_bit_cast(__hip_bfloat16, x));
}
static __device__ __forceinline__ float dot4(f32x4 a, f32x4 b) {
  return a.x * b.x + a.y * b.y + a.z * b.z + a.w * b.w;
}

static __device__ __forceinline__ void gl_lds16(const unsigned short* g, unsigned short* l) {
  __builtin_amdgcn_global_load_lds(
      (const __attribute__((address_space(1))) void*)g,
      (__attribute__((address_space(3))) void*)l, 16, 0, 0);
}

// ---------------- kernel 1: Mt = Wk^T x Wq directly from f32 (transpose fused) --------
// Mt[e][d] = sum_c Wk[c][e] * Wq[c][d].  64x64 output tile per block, 256 blocks.
// Both operands staged f32 -> bf16 with transpose-on-stage (8x ds_write_b16/thread/iter).
__global__ __launch_bounds__(256) void mt_fused(const float* __restrict__ Wq,
                                                const float* __restrict__ Wk,
                                                unsigned short* __restrict__ Mt) {
  __shared__ __align__(16) unsigned short As[64 * 32];   // As[e][c] = Wk[c][e]
  __shared__ __align__(16) unsigned short Bs[64 * 32];   // Bs[d][c] = Wq[c][d]
  const int tid = threadIdx.x;
  const int lane = tid & 63;
  const int wave = tid >> 6;
  const int wr = wave >> 1, wc = wave & 1;
  const size_t bm = (size_t)blockIdx.x * 64;   // e-tile
  const size_t bn = (size_t)blockIdx.y * 64;   // d-tile

  f32x4 acc[2][2];
  #pragma unroll
  for (int m = 0; m < 2; ++m)
    #pragma unroll
    for (int n = 0; n < 2; ++n)
      acc[m][n] = (f32x4){0.f, 0.f, 0.f, 0.f};

  const int cloc = tid >> 3;        // 0..31 (c within tile)
  const int e8 = (tid & 7) * 8;     // 0,8,..,56 (row-octet within tile)
  const int kg = lane >> 4;
  const int rowf = lane & 15;

  for (int kt = 0; kt < DIM; kt += 32) {
    const size_t c = kt + cloc;
    f32x4 a0 = *(const f32x4*)(Wk + c * DIM + bm + e8);
    f32x4 a1 = *(const f32x4*)(Wk + c * DIM + bm + e8 + 4);
    f32x4 b0 = *(const f32x4*)(Wq + c * DIM + bn + e8);
    f32x4 b1 = *(const f32x4*)(Wq + c * DIM + bn + e8 + 4);
    As[(e8 + 0) * 32 + cloc] = f2bf(a0.x); As[(e8 + 1) * 32 + cloc] = f2bf(a0.y);
    As[(e8 + 2) * 32 + cloc] = f2bf(a0.z); As[(e8 + 3) * 32 + cloc] = f2bf(a0.w);
    As[(e8 + 4) * 32 + cloc] = f2bf(a1.x); As[(e8 + 5) * 32 + cloc] = f2bf(a1.y);
    As[(e8 + 6) * 32 + cloc] = f2bf(a1.z); As[(e8 + 7) * 32 + cloc] = f2bf(a1.w);
    Bs[(e8 + 0) * 32 + cloc] = f2bf(b0.x); Bs[(e8 + 1) * 32 + cloc] = f2bf(b0.y);
    Bs[(e8 + 2) * 32 + cloc] = f2bf(b0.z); Bs[(e8 + 3) * 32 + cloc] = f2bf(b0.w);
    Bs[(e8 + 4) * 32 + cloc] = f2bf(b1.x); Bs[(e8 + 5) * 32 + cloc] = f2bf(b1.y);
    Bs[(e8 + 6) * 32 + cloc] = f2bf(b1.z); Bs[(e8 + 7) * 32 + cloc] = f2bf(b1.w);
    __syncthreads();
    short8 af[2], bfr[2];
    #pragma unroll
    for (int m = 0; m < 2; ++m)
      af[m] = *(const short8*)(As + ((wr * 32 + m * 16 + rowf) * 32 + kg * 8));
    #pragma unroll
    for (int n = 0; n < 2; ++n)
      bfr[n] = *(const short8*)(Bs + ((wc * 32 + n * 16 + rowf) * 32 + kg * 8));
    #pragma unroll
    for (int m = 0; m < 2; ++m)
      #pragma unroll
      for (int n = 0; n < 2; ++n)
        acc[m][n] = __builtin_amdgcn_mfma_f32_16x16x32_bf16(af[m], bfr[n], acc[m][n], 0, 0, 0);
    __syncthreads();
  }

  const int rq = (lane >> 4) * 4;
  const int colf = lane & 15;
  #pragma unroll
  for (int m = 0; m < 2; ++m)
    #pragma unroll
    for (int n = 0; n < 2; ++n)
      #pragma unroll
      for (int i = 0; i < 4; ++i)
        Mt[(bm + wr * 32 + m * 16 + rq + i) * DIM + bn + wc * 32 + n * 16 + colf] =
            f2bf(acc[m][n][i]);
}

// ---------------- kernel 2: u = query(f32) x Mt^T, 128x128, BK=32 ----------------
__global__ __launch_bounds__(256) void gemm_u(const float* __restrict__ Af,
                                              const unsigned short* __restrict__ B,
                                              unsigned short* __restrict__ C,
                                              int ntN, int ldc) {
  __shared__ __align__(16) unsigned short As[128 * 32];   // 8 KB
  __shared__ __align__(16) unsigned short Bs[128 * 32];   // 8 KB

  const int cpx = gridDim.x >> 3;          // XCD swizzle (512 % 8 == 0)
  const int wg = (blockIdx.x & 7) * cpx + (blockIdx.x >> 3);
  const size_t bm = (size_t)(wg / ntN) * 128;
  const size_t bn = (size_t)(wg % ntN) * 128;

  const int tid = threadIdx.x;
  const int lane = tid & 63;
  const int wave = tid >> 6;
  const int wr = wave >> 1, wc = wave & 1;

  f32x4 acc[4][4];
  #pragma unroll
  for (int m = 0; m < 4; ++m)
    #pragma unroll
    for (int n = 0; n < 4; ++n)
      acc[m][n] = (f32x4){0.f, 0.f, 0.f, 0.f};

  const int kg = lane >> 4;
  const int rowf = lane & 15;
  const int br0 = tid >> 2;
  const int bcc = (tid & 3) * 8;

  for (int kt = 0; kt < DIM; kt += 32) {
    gl_lds16(B + (bn + br0) * DIM + kt + bcc, Bs + tid * 8);
    gl_lds16(B + (bn + 64 + br0) * DIM + kt + bcc, Bs + 2048 + tid * 8);
    #pragma unroll
    for (int it = 0; it < 4; ++it) {
      int c = it * 256 + tid;
      int r = c >> 3;
      int ko = (c & 7) * 4;
      f32x4 f = *(const f32x4*)(Af + (bm + r) * DIM + kt + ko);
      ushort4 o;
      o.x = f2bf(f.x); o.y = f2bf(f.y); o.z = f2bf(f.z); o.w = f2bf(f.w);
      *(ushort4*)(As + r * 32 + ko) = o;
    }
    __syncthreads();
    short8 af[4], bfr[4];
    #pragma unroll
    for (int m = 0; m < 4; ++m)
      af[m] = *(const short8*)(As + ((wr * 64 + m * 16 + rowf) * 32 + kg * 8));
    #pragma unroll
    for (int n = 0; n < 4; ++n)
      bfr[n] = *(const short8*)(Bs + ((wc * 64 + n * 16 + rowf) * 32 + kg * 8));
    #pragma unroll
    for (int m = 0; m < 4; ++m)
      #pragma unroll
      for (int n = 0; n < 4; ++n)
        acc[m][n] = __builtin_amdgcn_mfma_f32_16x16x32_bf16(af[m], bfr[n], acc[m][n], 0, 0, 0);
    __syncthreads();
  }

  const int rq = (lane >> 4) * 4;
  const int colf = lane & 15;
  #pragma unroll
  for (int m = 0; m < 4; ++m)
    #pragma unroll
    for (int n = 0; n < 4; ++n)
      #pragma unroll
      for (int i = 0; i < 4; ++i) {
        size_t row = bm + wr * 64 + m * 16 + rq + i;
        size_t col = bn + wc * 64 + n * 16 + colf;
        C[row * (size_t)ldc + col] = f2bf(acc[m][n][i]);
      }
}

// ---------------- kernel 3: fused attention epilogue (8192 blocks) ----------------
// u bf16 strided in d_out (row b at element b*2048); q read as f32 (exact residual).
// All 32 K/V loads issued before any dependent arithmetic (max MLP).
__global__ __launch_bounds__(256) void epilogue(const float* __restrict__ query,
                                                const float* __restrict__ key,
                                                const float* __restrict__ value,
                                                const float* __restrict__ Wa,
                                                const float* __restrict__ ba,
                                                const unsigned short* __restrict__ u,
                                                float* __restrict__ out) {
  const int b = blockIdx.x;
  const int tid = threadIdx.x;
  const int lane = tid & 63, wave = tid >> 6;
  const f32x4* k4 = (const f32x4*)(key + (size_t)b * KV * DIM);
  const f32x4* v4 = (const f32x4*)(value + (size_t)b * KV * DIM);

  f32x4 qv = ((const f32x4*)(query + (size_t)b * DIM))[tid];
  ushort4 ub = ((const ushort4*)(u + (size_t)b * 2048))[tid];
  f32x4 uv;
  uv.x = bf2f(ub.x); uv.y = bf2f(ub.y); uv.z = bf2f(ub.z); uv.w = bf2f(ub.w);
  f32x4 wv = ((const f32x4*)Wa)[tid];

  // issue ALL V and K loads before the dependent dot/reduce chains
  f32x4 vv[16];
  #pragma unroll
  for (int j = 0; j < 16; ++j)
    vv[j] = __builtin_nontemporal_load(v4 + j * 256 + tid);

  float s[17];
  s[0] = dot4(qv, uv);
  float ad = dot4(qv, wv);
  #pragma unroll
  for (int j = 1; j <= 16; ++j) {
    f32x4 kv = __builtin_nontemporal_load(k4 + (j - 1) * 256 + tid);
    s[j] = dot4(uv, kv);
  }

  #pragma unroll
  for (int m = 32; m >= 1; m >>= 1) {
    #pragma unroll
    for (int j = 0; j < 17; ++j) s[j] += __shfl_xor(s[j], m);
    ad += __shfl_xor(ad, m);
  }
  __shared__ float red[4][18];
  if (lane == 0) {
    #pragma unroll
    for (int j = 0; j < 17; ++j) red[wave][j] = s[j];
    red[wave][17] = ad;
  }
  __syncthreads();

  float wt[17];
  float mx = -1e30f;
  #pragma unroll
  for (int j = 0; j < 17; ++j) {
    float t = (red[0][j] + red[1][j] + red[2][j] + red[3][j]) * 0.03125f;
    wt[j] = t;
    mx = fmaxf(mx, t);
  }
  float den = 0.f;
  #pragma unroll
  for (int j = 0; j < 17; ++j) {
    wt[j] = expf(wt[j] - mx);
    den += wt[j];
  }
  float adt = red[0][17] + red[1][17] + red[2][17] + red[3][17] + ba[0];
  float alpha = 1.0f / (1.0f + expf(-adt));
  float am = alpha / den;

  f32x4 acc = qv * wt[0];
  #pragma unroll
  for (int j = 1; j <= 16; ++j) acc += vv[j - 1] * wt[j];
  f32x4 t = qv + acc * am;

  float ssp = dot4(t, t);
  #pragma unroll
  for (int m = 32; m >= 1; m >>= 1) ssp += __shfl_xor(ssp, m);
  __shared__ float red2[4];
  if (lane == 0) red2[wave] = ssp;
  __syncthreads();
  float nrm = sqrtf(red2[0] + red2[1] + red2[2] + red2[3]);
  float inv = 1.0f / fmaxf(nrm, 1e-12f);

  __builtin_nontemporal_store(t * inv, (f32x4*)(out + (size_t)b * DIM) + tid);
}

// ---------------- launcher ----------------
extern "C" void kernel_launch(void* const* d_in, const int* in_sizes, int n_in,
                              void* d_out, int out_size, void* d_ws, size_t ws_size,
                              hipStream_t stream) {
  const float* query = (const float*)d_in[0];
  const float* key   = (const float*)d_in[1];
  const float* value = (const float*)d_in[2];
  const float* Wq    = (const float*)d_in[3];
  const float* Wk    = (const float*)d_in[4];
  const float* Wa    = (const float*)d_in[5];
  const float* ba    = (const float*)d_in[6];

  unsigned short* Mt  = (unsigned short*)d_ws;              // 2 MiB
  unsigned short* ubf = (unsigned short*)d_out;             // strided bf16 u inside d_out

  // Mt = Wk^T x Wq (1024^3, f32 in, bf16 out; transpose fused into staging)
  mt_fused<<<dim3(16, 16), 256, 0, stream>>>(Wq, Wk, Mt);
  // u = query(f32) x Mt^T, BK=32, inline conversion; bf16 out strided ldc=2048
  gemm_u<<<512, 256, 0, stream>>>(query, Mt, ubf, DIM / 128, 2048);
  // fused scores/softmax/attn/gate/normalize (f32 q)
  epilogue<<<BATCH, 256, 0, stream>>>(query, key, value, Wa, ba, ubf, (float*)d_out);
}

// Round 8
// 241.677 us; speedup vs baseline: 1.0654x; 1.0654x over previous
//
#include <hip/hip_runtime.h>
#include <hip/hip_bf16.h>

#define DIM   1024
#define BATCH 8192
#define KV    16

typedef __attribute__((ext_vector_type(4))) float f32x4;
typedef __attribute__((ext_vector_type(8))) short short8;

static __device__ __forceinline__ unsigned short f2bf(float x) {
  return __builtin_bit_cast(unsigned short, __float2bfloat16(x));
}
static __device__ __forceinline__ float bf2f(unsigned short x) {
  return __bfloat162float(__builtin_bit_cast(__hip_bfloat16, x));
}
static __device__ __forceinline__ float dot4(f32x4 a, f32x4 b) {
  return a.x * b.x + a.y * b.y + a.z * b.z + a.w * b.w;
}

static __device__ __forceinline__ void gl_lds16(const unsigned short* g, unsigned short* l) {
  __builtin_amdgcn_global_load_lds(
      (const __attribute__((address_space(1))) void*)g,
      (__attribute__((address_space(3))) void*)l, 16, 0, 0);
}

// ---------------- kernel 1: Wq,Wk f32 -> transposed bf16 ----------------
__global__ __launch_bounds__(256) void transpose_w(const float* __restrict__ Wq,
                                                   const float* __restrict__ Wk,
                                                   unsigned short* __restrict__ WqT,
                                                   unsigned short* __restrict__ WkT) {
  __shared__ float tile[32][33];
  const float* src = blockIdx.z ? Wk : Wq;
  unsigned short* dst = blockIdx.z ? WkT : WqT;
  int tx = threadIdx.x & 31, ty = threadIdx.x >> 5;
  int x = blockIdx.x * 32 + tx;
  int y0 = blockIdx.y * 32;
  #pragma unroll
  for (int i = ty; i < 32; i += 8)
    tile[i][tx] = src[(size_t)(y0 + i) * DIM + x];
  __syncthreads();
  int x2 = blockIdx.y * 32 + tx;
  int y2 = blockIdx.x * 32;
  #pragma unroll
  for (int i = ty; i < 32; i += 8)
    dst[(size_t)(y2 + i) * DIM + x2] = f2bf(tile[tx][i]);
}

// ---------------- kernel 2: Mt = WkT x WqT^T, 64x64 tiles (256 blocks) ----------------
__global__ __launch_bounds__(256) void gemm_nt64(const unsigned short* __restrict__ A,
                                                 const unsigned short* __restrict__ B,
                                                 unsigned short* __restrict__ C,
                                                 int N, int K) {
  __shared__ __align__(16) unsigned short As[64 * 32];
  __shared__ __align__(16) unsigned short Bs[64 * 32];
  const int tid = threadIdx.x;
  const int lane = tid & 63;
  const int wave = tid >> 6;
  const int wr = wave >> 1, wc = wave & 1;
  const size_t bm = (size_t)blockIdx.x * 64;
  const size_t bn = (size_t)blockIdx.y * 64;

  f32x4 acc[2][2];
  #pragma unroll
  for (int m = 0; m < 2; ++m)
    #pragma unroll
    for (int n = 0; n < 2; ++n)
      acc[m][n] = (f32x4){0.f, 0.f, 0.f, 0.f};

  const int r0 = tid >> 2;
  const int cc = (tid & 3) * 8;
  const int kg = lane >> 4;
  const int rowf = lane & 15;

  for (int kt = 0; kt < K; kt += 32) {
    gl_lds16(A + (bm + r0) * K + kt + cc, As + tid * 8);
    gl_lds16(B + (bn + r0) * K + kt + cc, Bs + tid * 8);
    __syncthreads();
    short8 af[2], bfr[2];
    #pragma unroll
    for (int m = 0; m < 2; ++m)
      af[m] = *(const short8*)(As + ((wr * 32 + m * 16 + rowf) * 32 + kg * 8));
    #pragma unroll
    for (int n = 0; n < 2; ++n)
      bfr[n] = *(const short8*)(Bs + ((wc * 32 + n * 16 + rowf) * 32 + kg * 8));
    #pragma unroll
    for (int m = 0; m < 2; ++m)
      #pragma unroll
      for (int n = 0; n < 2; ++n)
        acc[m][n] = __builtin_amdgcn_mfma_f32_16x16x32_bf16(af[m], bfr[n], acc[m][n], 0, 0, 0);
    __syncthreads();
  }

  const int rq = (lane >> 4) * 4;
  const int colf = lane & 15;
  #pragma unroll
  for (int m = 0; m < 2; ++m)
    #pragma unroll
    for (int n = 0; n < 2; ++n)
      #pragma unroll
      for (int i = 0; i < 4; ++i)
        C[(bm + wr * 32 + m * 16 + rq + i) * N + bn + wc * 32 + n * 16 + colf] =
            f2bf(acc[m][n][i]);
}

// ---------------- kernel 3: u = query(f32) x Mt^T, 128x128, BK=32, T14 A-prefetch ------
// A staged reg-side with inline f32->bf16 conversion; NEXT tile's A f32 loads issued
// right after the barrier so HBM latency hides under the MFMA cluster.
// B staged via global_load_lds. bf16 out, strided into d_out.
__global__ __launch_bounds__(256) void gemm_u(const float* __restrict__ Af,
                                              const unsigned short* __restrict__ B,
                                              unsigned short* __restrict__ C,
                                              int ntN, int ldc) {
  __shared__ __align__(16) unsigned short As[128 * 32];   // 8 KB
  __shared__ __align__(16) unsigned short Bs[128 * 32];   // 8 KB

  const int cpx = gridDim.x >> 3;          // XCD swizzle (512 % 8 == 0)
  const int wg = (blockIdx.x & 7) * cpx + (blockIdx.x >> 3);
  const size_t bm = (size_t)(wg / ntN) * 128;
  const size_t bn = (size_t)(wg % ntN) * 128;

  const int tid = threadIdx.x;
  const int lane = tid & 63;
  const int wave = tid >> 6;
  const int wr = wave >> 1, wc = wave & 1;

  f32x4 acc[4][4];
  #pragma unroll
  for (int m = 0; m < 4; ++m)
    #pragma unroll
    for (int n = 0; n < 4; ++n)
      acc[m][n] = (f32x4){0.f, 0.f, 0.f, 0.f};

  const int kg = lane >> 4;
  const int rowf = lane & 15;
  const int br0 = tid >> 2;
  const int bcc = (tid & 3) * 8;
  // A chunk mapping: c = it*256+tid; row = c>>3; koff = (c&7)*4
  const int ar[4] = { (0 * 256 + tid) >> 3, (1 * 256 + tid) >> 3,
                      (2 * 256 + tid) >> 3, (3 * 256 + tid) >> 3 };
  const int ak = (tid & 7) * 4;

  // prologue: prefetch A(kt=0)
  f32x4 pref[4];
  #pragma unroll
  for (int it = 0; it < 4; ++it)
    pref[it] = *(const f32x4*)(Af + (bm + ar[it]) * DIM + 0 + ak);

  for (int kt = 0; kt < DIM; kt += 32) {
    // B: global_load_lds (2 x 16B per thread)
    gl_lds16(B + (bn + br0) * DIM + kt + bcc, Bs + tid * 8);
    gl_lds16(B + (bn + 64 + br0) * DIM + kt + bcc, Bs + 2048 + tid * 8);
    // A: convert prefetched regs -> LDS
    #pragma unroll
    for (int it = 0; it < 4; ++it) {
      ushort4 o;
      o.x = f2bf(pref[it].x); o.y = f2bf(pref[it].y);
      o.z = f2bf(pref[it].z); o.w = f2bf(pref[it].w);
      *(ushort4*)(As + ar[it] * 32 + ak) = o;
    }
    __syncthreads();
    // T14: issue NEXT tile's A loads now; they complete under the MFMAs
    if (kt + 32 < DIM) {
      #pragma unroll
      for (int it = 0; it < 4; ++it)
        pref[it] = *(const f32x4*)(Af + (bm + ar[it]) * DIM + kt + 32 + ak);
    }
    short8 af[4], bfr[4];
    #pragma unroll
    for (int m = 0; m < 4; ++m)
      af[m] = *(const short8*)(As + ((wr * 64 + m * 16 + rowf) * 32 + kg * 8));
    #pragma unroll
    for (int n = 0; n < 4; ++n)
      bfr[n] = *(const short8*)(Bs + ((wc * 64 + n * 16 + rowf) * 32 + kg * 8));
    #pragma unroll
    for (int m = 0; m < 4; ++m)
      #pragma unroll
      for (int n = 0; n < 4; ++n)
        acc[m][n] = __builtin_amdgcn_mfma_f32_16x16x32_bf16(af[m], bfr[n], acc[m][n], 0, 0, 0);
    __syncthreads();
  }

  const int rq = (lane >> 4) * 4;
  const int colf = lane & 15;
  #pragma unroll
  for (int m = 0; m < 4; ++m)
    #pragma unroll
    for (int n = 0; n < 4; ++n)
      #pragma unroll
      for (int i = 0; i < 4; ++i) {
        size_t row = bm + wr * 64 + m * 16 + rq + i;
        size_t col = bn + wc * 64 + n * 16 + colf;
        C[row * (size_t)ldc + col] = f2bf(acc[m][n][i]);
      }
}

// ---------------- kernel 4: fused attention epilogue (8192 blocks) ----------------
// u bf16 strided in d_out (row b at element b*2048); q read as f32 (exact residual).
__global__ __launch_bounds__(256) void epilogue(const float* __restrict__ query,
                                                const float* __restrict__ key,
                                                const float* __restrict__ value,
                                                const float* __restrict__ Wa,
                                                const float* __restrict__ ba,
                                                const unsigned short* __restrict__ u,
                                                float* __restrict__ out) {
  const int b = blockIdx.x;
  const int tid = threadIdx.x;
  const int lane = tid & 63, wave = tid >> 6;
  const f32x4* k4 = (const f32x4*)(key + (size_t)b * KV * DIM);
  const f32x4* v4 = (const f32x4*)(value + (size_t)b * KV * DIM);

  f32x4 qv = ((const f32x4*)(query + (size_t)b * DIM))[tid];
  ushort4 ub = ((const ushort4*)(u + (size_t)b * 2048))[tid];
  f32x4 uv;
  uv.x = bf2f(ub.x); uv.y = bf2f(ub.y); uv.z = bf2f(ub.z); uv.w = bf2f(ub.w);
  f32x4 wv = ((const f32x4*)Wa)[tid];

  float s[17];
  s[0] = dot4(qv, uv);
  float ad = dot4(qv, wv);
  #pragma unroll
  for (int j = 1; j <= 16; ++j) {
    f32x4 kv = __builtin_nontemporal_load(k4 + (j - 1) * 256 + tid);
    s[j] = dot4(uv, kv);
  }

  // prefetch all V rows BEFORE the reduction chains
  f32x4 vv[16];
  #pragma unroll
  for (int j = 0; j < 16; ++j)
    vv[j] = __builtin_nontemporal_load(v4 + j * 256 + tid);

  #pragma unroll
  for (int m = 32; m >= 1; m >>= 1) {
    #pragma unroll
    for (int j = 0; j < 17; ++j) s[j] += __shfl_xor(s[j], m);
    ad += __shfl_xor(ad, m);
  }
  __shared__ float red[4][18];
  if (lane == 0) {
    #pragma unroll
    for (int j = 0; j < 17; ++j) red[wave][j] = s[j];
    red[wave][17] = ad;
  }
  __syncthreads();

  float wt[17];
  float mx = -1e30f;
  #pragma unroll
  for (int j = 0; j < 17; ++j) {
    float t = (red[0][j] + red[1][j] + red[2][j] + red[3][j]) * 0.03125f;
    wt[j] = t;
    mx = fmaxf(mx, t);
  }
  float den = 0.f;
  #pragma unroll
  for (int j = 0; j < 17; ++j) {
    wt[j] = expf(wt[j] - mx);
    den += wt[j];
  }
  float adt = red[0][17] + red[1][17] + red[2][17] + red[3][17] + ba[0];
  float alpha = 1.0f / (1.0f + expf(-adt));
  float am = alpha / den;

  f32x4 acc = qv * wt[0];
  #pragma unroll
  for (int j = 1; j <= 16; ++j) acc += vv[j - 1] * wt[j];
  f32x4 t = qv + acc * am;

  float ssp = dot4(t, t);
  #pragma unroll
  for (int m = 32; m >= 1; m >>= 1) ssp += __shfl_xor(ssp, m);
  __shared__ float red2[4];
  if (lane == 0) red2[wave] = ssp;
  __syncthreads();
  float nrm = sqrtf(red2[0] + red2[1] + red2[2] + red2[3]);
  float inv = 1.0f / fmaxf(nrm, 1e-12f);

  __builtin_nontemporal_store(t * inv, (f32x4*)(out + (size_t)b * DIM) + tid);
}

// ---------------- launcher ----------------
extern "C" void kernel_launch(void* const* d_in, const int* in_sizes, int n_in,
                              void* d_out, int out_size, void* d_ws, size_t ws_size,
                              hipStream_t stream) {
  const float* query = (const float*)d_in[0];
  const float* key   = (const float*)d_in[1];
  const float* value = (const float*)d_in[2];
  const float* Wq    = (const float*)d_in[3];
  const float* Wk    = (const float*)d_in[4];
  const float* Wa    = (const float*)d_in[5];
  const float* ba    = (const float*)d_in[6];

  unsigned short* WqT = (unsigned short*)d_ws;              // 2 MiB
  unsigned short* WkT = WqT + (size_t)DIM * DIM;            // 2 MiB
  unsigned short* Mt  = WkT + (size_t)DIM * DIM;            // 2 MiB
  unsigned short* ubf = (unsigned short*)d_out;             // strided bf16 u inside d_out

  // W transposes (bf16)
  transpose_w<<<dim3(32, 32, 2), 256, 0, stream>>>(Wq, Wk, WqT, WkT);
  // Mt = WkT x WqT^T  (1024^3, bf16 out)
  gemm_nt64<<<dim3(16, 16), 256, 0, stream>>>(WkT, WqT, Mt, DIM, DIM);
  // u = query(f32) x Mt^T, BK=32, inline conversion + T14 prefetch; strided ldc=2048
  gemm_u<<<512, 256, 0, stream>>>(query, Mt, ubf, DIM / 128, 2048);
  // fused scores/softmax/attn/gate/normalize (f32 q)
  epilogue<<<BATCH, 256, 0, stream>>>(query, key, value, Wa, ba, ubf, (float*)d_out);
}

// Round 9
// 238.257 us; speedup vs baseline: 1.0807x; 1.0144x over previous
//
#include <hip/hip_runtime.h>
#include <hip/hip_bf16.h>

#define DIM   1024
#define BATCH 8192
#define KV    16

typedef __attribute__((ext_vector_type(4))) float f32x4;
typedef __attribute__((ext_vector_type(8))) short short8;

static __device__ __forceinline__ unsigned short f2bf(float x) {
  return __builtin_bit_cast(unsigned short, __float2bfloat16(x));
}
static __device__ __forceinline__ float bf2f(unsigned short x) {
  return __bfloat162float(__builtin_bit_cast(__hip_bfloat16, x));
}
static __device__ __forceinline__ float dot4(f32x4 a, f32x4 b) {
  return a.x * b.x + a.y * b.y + a.z * b.z + a.w * b.w;
}

static __device__ __forceinline__ void gl_lds16(const unsigned short* g, unsigned short* l) {
  __builtin_amdgcn_global_load_lds(
      (const __attribute__((address_space(1))) void*)g,
      (__attribute__((address_space(3))) void*)l, 16, 0, 0);
}

// ---------------- kernel 1: Wq,Wk f32 -> transposed bf16 ----------------
__global__ __launch_bounds__(256) void transpose_w(const float* __restrict__ Wq,
                                                   const float* __restrict__ Wk,
                                                   unsigned short* __restrict__ WqT,
                                                   unsigned short* __restrict__ WkT) {
  __shared__ float tile[32][33];
  const float* src = blockIdx.z ? Wk : Wq;
  unsigned short* dst = blockIdx.z ? WkT : WqT;
  int tx = threadIdx.x & 31, ty = threadIdx.x >> 5;
  int x = blockIdx.x * 32 + tx;
  int y0 = blockIdx.y * 32;
  #pragma unroll
  for (int i = ty; i < 32; i += 8)
    tile[i][tx] = src[(size_t)(y0 + i) * DIM + x];
  __syncthreads();
  int x2 = blockIdx.y * 32 + tx;
  int y2 = blockIdx.x * 32;
  #pragma unroll
  for (int i = ty; i < 32; i += 8)
    dst[(size_t)(y2 + i) * DIM + x2] = f2bf(tile[tx][i]);
}

// ---------------- kernel 2: Mt = WkT x WqT^T, 64x64 tiles (256 blocks) ----------------
__global__ __launch_bounds__(256) void gemm_nt64(const unsigned short* __restrict__ A,
                                                 const unsigned short* __restrict__ B,
                                                 unsigned short* __restrict__ C,
                                                 int N, int K) {
  __shared__ __align__(16) unsigned short As[64 * 32];
  __shared__ __align__(16) unsigned short Bs[64 * 32];
  const int tid = threadIdx.x;
  const int lane = tid & 63;
  const int wave = tid >> 6;
  const int wr = wave >> 1, wc = wave & 1;
  const size_t bm = (size_t)blockIdx.x * 64;
  const size_t bn = (size_t)blockIdx.y * 64;

  f32x4 acc[2][2];
  #pragma unroll
  for (int m = 0; m < 2; ++m)
    #pragma unroll
    for (int n = 0; n < 2; ++n)
      acc[m][n] = (f32x4){0.f, 0.f, 0.f, 0.f};

  const int r0 = tid >> 2;
  const int cc = (tid & 3) * 8;
  const int kg = lane >> 4;
  const int rowf = lane & 15;

  for (int kt = 0; kt < K; kt += 32) {
    gl_lds16(A + (bm + r0) * K + kt + cc, As + tid * 8);
    gl_lds16(B + (bn + r0) * K + kt + cc, Bs + tid * 8);
    __syncthreads();
    short8 af[2], bfr[2];
    #pragma unroll
    for (int m = 0; m < 2; ++m)
      af[m] = *(const short8*)(As + ((wr * 32 + m * 16 + rowf) * 32 + kg * 8));
    #pragma unroll
    for (int n = 0; n < 2; ++n)
      bfr[n] = *(const short8*)(Bs + ((wc * 32 + n * 16 + rowf) * 32 + kg * 8));
    #pragma unroll
    for (int m = 0; m < 2; ++m)
      #pragma unroll
      for (int n = 0; n < 2; ++n)
        acc[m][n] = __builtin_amdgcn_mfma_f32_16x16x32_bf16(af[m], bfr[n], acc[m][n], 0, 0, 0);
    __syncthreads();
  }

  const int rq = (lane >> 4) * 4;
  const int colf = lane & 15;
  #pragma unroll
  for (int m = 0; m < 2; ++m)
    #pragma unroll
    for (int n = 0; n < 2; ++n)
      #pragma unroll
      for (int i = 0; i < 4; ++i)
        C[(bm + wr * 32 + m * 16 + rq + i) * N + bn + wc * 32 + n * 16 + colf] =
            f2bf(acc[m][n][i]);
}

// ---------------- kernel 3: u = query(f32) x Mt^T, 128x128, BK=32, 8 waves ----------
// 512 threads (8 waves, 2x4): each wave owns a 64x32 sub-tile (acc[4][2]).
// A reg-staged with inline f32->bf16 cvt + T14 next-tile prefetch; B via global_load_lds.
// 16 waves/CU (vs 8 at 4-wave blocks) -> staging latency hidden by TLP.
__global__ __launch_bounds__(512) void gemm_u(const float* __restrict__ Af,
                                              const unsigned short* __restrict__ B,
                                              unsigned short* __restrict__ C,
                                              int ntN, int ldc) {
  __shared__ __align__(16) unsigned short As[128 * 32];   // 8 KB
  __shared__ __align__(16) unsigned short Bs[128 * 32];   // 8 KB

  const int cpx = gridDim.x >> 3;          // XCD swizzle (512 % 8 == 0)
  const int wg = (blockIdx.x & 7) * cpx + (blockIdx.x >> 3);
  const size_t bm = (size_t)(wg / ntN) * 128;
  const size_t bn = (size_t)(wg % ntN) * 128;

  const int tid = threadIdx.x;
  const int lane = tid & 63;
  const int wave = tid >> 6;               // 0..7
  const int wr = wave >> 2, wc = wave & 3; // 2 x 4 wave grid

  f32x4 acc[4][2];
  #pragma unroll
  for (int m = 0; m < 4; ++m)
    #pragma unroll
    for (int n = 0; n < 2; ++n)
      acc[m][n] = (f32x4){0.f, 0.f, 0.f, 0.f};

  const int kg = lane >> 4;
  const int rowf = lane & 15;
  const int br0 = tid >> 2;                // B chunk row (512 chunks, 1/thread)
  const int bcc = (tid & 3) * 8;
  // A chunk mapping: c = it*512 + tid; row = c>>3; koff = (c&7)*4  (2/thread)
  const int ar0 = tid >> 3;
  const int ak = (tid & 7) * 4;

  // prologue: prefetch A(kt=0)
  f32x4 pref[2];
  pref[0] = *(const f32x4*)(Af + (bm + ar0) * DIM + ak);
  pref[1] = *(const f32x4*)(Af + (bm + 64 + ar0) * DIM + ak);

  for (int kt = 0; kt < DIM; kt += 32) {
    // B: global_load_lds (1 x 16B per thread)
    gl_lds16(B + (bn + br0) * DIM + kt + bcc, Bs + tid * 8);
    // A: convert prefetched regs -> LDS (linear, conflict-free)
    {
      ushort4 o0, o1;
      o0.x = f2bf(pref[0].x); o0.y = f2bf(pref[0].y);
      o0.z = f2bf(pref[0].z); o0.w = f2bf(pref[0].w);
      o1.x = f2bf(pref[1].x); o1.y = f2bf(pref[1].y);
      o1.z = f2bf(pref[1].z); o1.w = f2bf(pref[1].w);
      *(ushort4*)(As + ar0 * 32 + ak) = o0;
      *(ushort4*)(As + (64 + ar0) * 32 + ak) = o1;
    }
    __syncthreads();
    // T14: issue NEXT tile's A loads now; they complete under the MFMAs
    if (kt + 32 < DIM) {
      pref[0] = *(const f32x4*)(Af + (bm + ar0) * DIM + kt + 32 + ak);
      pref[1] = *(const f32x4*)(Af + (bm + 64 + ar0) * DIM + kt + 32 + ak);
    }
    short8 af[4], bfr[2];
    #pragma unroll
    for (int m = 0; m < 4; ++m)
      af[m] = *(const short8*)(As + ((wr * 64 + m * 16 + rowf) * 32 + kg * 8));
    #pragma unroll
    for (int n = 0; n < 2; ++n)
      bfr[n] = *(const short8*)(Bs + ((wc * 32 + n * 16 + rowf) * 32 + kg * 8));
    #pragma unroll
    for (int m = 0; m < 4; ++m)
      #pragma unroll
      for (int n = 0; n < 2; ++n)
        acc[m][n] = __builtin_amdgcn_mfma_f32_16x16x32_bf16(af[m], bfr[n], acc[m][n], 0, 0, 0);
    __syncthreads();
  }

  const int rq = (lane >> 4) * 4;
  const int colf = lane & 15;
  #pragma unroll
  for (int m = 0; m < 4; ++m)
    #pragma unroll
    for (int n = 0; n < 2; ++n)
      #pragma unroll
      for (int i = 0; i < 4; ++i) {
        size_t row = bm + wr * 64 + m * 16 + rq + i;
        size_t col = bn + wc * 32 + n * 16 + colf;
        C[row * (size_t)ldc + col] = f2bf(acc[m][n][i]);
      }
}

// ---------------- kernel 4: fused attention epilogue (8192 blocks) ----------------
// u bf16 strided in d_out (row b at element b*2048); q read as f32 (exact residual).
__global__ __launch_bounds__(256) void epilogue(const float* __restrict__ query,
                                                const float* __restrict__ key,
                                                const float* __restrict__ value,
                                                const float* __restrict__ Wa,
                                                const float* __restrict__ ba,
                                                const unsigned short* __restrict__ u,
                                                float* __restrict__ out) {
  const int b = blockIdx.x;
  const int tid = threadIdx.x;
  const int lane = tid & 63, wave = tid >> 6;
  const f32x4* k4 = (const f32x4*)(key + (size_t)b * KV * DIM);
  const f32x4* v4 = (const f32x4*)(value + (size_t)b * KV * DIM);

  f32x4 qv = ((const f32x4*)(query + (size_t)b * DIM))[tid];
  ushort4 ub = ((const ushort4*)(u + (size_t)b * 2048))[tid];
  f32x4 uv;
  uv.x = bf2f(ub.x); uv.y = bf2f(ub.y); uv.z = bf2f(ub.z); uv.w = bf2f(ub.w);
  f32x4 wv = ((const f32x4*)Wa)[tid];

  float s[17];
  s[0] = dot4(qv, uv);
  float ad = dot4(qv, wv);
  #pragma unroll
  for (int j = 1; j <= 16; ++j) {
    f32x4 kv = __builtin_nontemporal_load(k4 + (j - 1) * 256 + tid);
    s[j] = dot4(uv, kv);
  }

  // prefetch all V rows BEFORE the reduction chains
  f32x4 vv[16];
  #pragma unroll
  for (int j = 0; j < 16; ++j)
    vv[j] = __builtin_nontemporal_load(v4 + j * 256 + tid);

  #pragma unroll
  for (int m = 32; m >= 1; m >>= 1) {
    #pragma unroll
    for (int j = 0; j < 17; ++j) s[j] += __shfl_xor(s[j], m);
    ad += __shfl_xor(ad, m);
  }
  __shared__ float red[4][18];
  if (lane == 0) {
    #pragma unroll
    for (int j = 0; j < 17; ++j) red[wave][j] = s[j];
    red[wave][17] = ad;
  }
  __syncthreads();

  float wt[17];
  float mx = -1e30f;
  #pragma unroll
  for (int j = 0; j < 17; ++j) {
    float t = (red[0][j] + red[1][j] + red[2][j] + red[3][j]) * 0.03125f;
    wt[j] = t;
    mx = fmaxf(mx, t);
  }
  float den = 0.f;
  #pragma unroll
  for (int j = 0; j < 17; ++j) {
    wt[j] = expf(wt[j] - mx);
    den += wt[j];
  }
  float adt = red[0][17] + red[1][17] + red[2][17] + red[3][17] + ba[0];
  float alpha = 1.0f / (1.0f + expf(-adt));
  float am = alpha / den;

  f32x4 acc = qv * wt[0];
  #pragma unroll
  for (int j = 1; j <= 16; ++j) acc += vv[j - 1] * wt[j];
  f32x4 t = qv + acc * am;

  float ssp = dot4(t, t);
  #pragma unroll
  for (int m = 32; m >= 1; m >>= 1) ssp += __shfl_xor(ssp, m);
  __shared__ float red2[4];
  if (lane == 0) red2[wave] = ssp;
  __syncthreads();
  float nrm = sqrtf(red2[0] + red2[1] + red2[2] + red2[3]);
  float inv = 1.0f / fmaxf(nrm, 1e-12f);

  __builtin_nontemporal_store(t * inv, (f32x4*)(out + (size_t)b * DIM) + tid);
}

// ---------------- launcher ----------------
extern "C" void kernel_launch(void* const* d_in, const int* in_sizes, int n_in,
                              void* d_out, int out_size, void* d_ws, size_t ws_size,
                              hipStream_t stream) {
  const float* query = (const float*)d_in[0];
  const float* key   = (const float*)d_in[1];
  const float* value = (const float*)d_in[2];
  const float* Wq    = (const float*)d_in[3];
  const float* Wk    = (const float*)d_in[4];
  const float* Wa    = (const float*)d_in[5];
  const float* ba    = (const float*)d_in[6];

  unsigned short* WqT = (unsigned short*)d_ws;              // 2 MiB
  unsigned short* WkT = WqT + (size_t)DIM * DIM;            // 2 MiB
  unsigned short* Mt  = WkT + (size_t)DIM * DIM;            // 2 MiB
  unsigned short* ubf = (unsigned short*)d_out;             // strided bf16 u inside d_out

  // W transposes (bf16)
  transpose_w<<<dim3(32, 32, 2), 256, 0, stream>>>(Wq, Wk, WqT, WkT);
  // Mt = WkT x WqT^T  (1024^3, bf16 out)
  gemm_nt64<<<dim3(16, 16), 256, 0, stream>>>(WkT, WqT, Mt, DIM, DIM);
  // u = query(f32) x Mt^T, 8-wave blocks, BK=32, T14 prefetch; strided ldc=2048
  gemm_u<<<512, 512, 0, stream>>>(query, Mt, ubf, DIM / 128, 2048);
  // fused scores/softmax/attn/gate/normalize (f32 q)
  epilogue<<<BATCH, 256, 0, stream>>>(query, key, value, Wa, ba, ubf, (float*)d_out);
}